// Round 1
// baseline (222.339 us; speedup 1.0000x reference)
//
#include <hip/hip_runtime.h>
#include <math.h>

#define T_STEPS 256
#define BS      512
#define N       2048
#define BLOCK   64                // ONE wave per batch element: no barriers, no LDS reduce
#define EPT     (N / BLOCK)       // 32 elements per thread
#define NP      (EPT / 2)         // 16 packed float2 per thread
#define NQ      (EPT / 4)         // 8 float4 loads per thread
#define FUDGE   1e-4f

typedef float v2f __attribute__((ext_vector_type(2)));
typedef float v4f __attribute__((ext_vector_type(4)));

// --- packed fp32 math (VOP3P, gfx90a+/gfx950). One instr = 2 lanes of fma. ---
__device__ __forceinline__ v2f pk_fma(v2f a, v2f b, v2f c) {
    v2f d;
    asm("v_pk_fma_f32 %0, %1, %2, %3" : "=v"(d) : "v"(a), "v"(b), "v"(c));
    return d;
}
__device__ __forceinline__ v2f pk_add(v2f a, v2f b) {
    v2f d;
    asm("v_pk_add_f32 %0, %1, %2" : "=v"(d) : "v"(a), "v"(b));
    return d;
}

// --- wave64 sum via DPP: lane 63 holds the wave total --------------------
template <int CTRL>
__device__ __forceinline__ float dpp_add(float v) {
    int sh = __builtin_amdgcn_update_dpp(0, __float_as_int(v), CTRL, 0xf, 0xf, true);
    return v + __int_as_float(sh);
}

__device__ __forceinline__ float wave_sum_lane63(float v) {
    v = dpp_add<0x111>(v);  // row_shr:1
    v = dpp_add<0x112>(v);  // row_shr:2
    v = dpp_add<0x114>(v);  // row_shr:4
    v = dpp_add<0x118>(v);  // row_shr:8
    v = dpp_add<0x142>(v);  // row_bcast:15
    v = dpp_add<0x143>(v);  // row_bcast:31
    return v;               // total valid in lane 63
}

__device__ __forceinline__ float bcast63(float v) {
    return __int_as_float(__builtin_amdgcn_readlane(__float_as_int(v), 63));
}

// R9: structural change. The 4-wave version spent ~300+ cy/step on the
// cross-wave reduce round-trip (DPP chain -> LDS write -> barrier with wave
// skew -> ds_read ~120cy -> combine) and ran all uniform scalar work 4x.
// This version: 1 wave per batch element (512 blocks x 64 threads, EPT=32),
// reduction is DPP + v_readlane only -- zero barriers, zero LDS in the loop
// (LDS only holds the per-step scalars). Element-wise math packed with
// v_pk_fma_f32 to halve the issue cost of the 4x-larger per-wave loop.
// ~200 VGPRs needed; __launch_bounds__(64,1) allows up to 512, no spill.
__global__ __launch_bounds__(BLOCK, 1)
void legacy_elbo_scan_kernel(
    const float* __restrict__ noises,   // [T, BS]
    const float* __restrict__ ys,       // [T]
    const float* __restrict__ qs,       // [T]
    const float* __restrict__ z_biases, // [N]
    const float* __restrict__ w_in,     // [N]
    const float* __restrict__ w_inq,    // [N]
    const float* __restrict__ p_llr,
    const float* __restrict__ p_llrd,
    const float* __restrict__ p_sigb,
    const float* __restrict__ p_oscale,
    const float* __restrict__ p_ufs,
    const float* __restrict__ p_lwd,
    const float* __restrict__ p_qscale,
    const float* __restrict__ p_tauq,
    const float* __restrict__ p_tauy,
    float* __restrict__ out)            // [T, BS]
{
    const int tid = threadIdx.x;        // == lane
    const int blk = blockIdx.x;         // batch index k

    __shared__ float ys_s[T_STEPS];
    __shared__ float qs_s[T_STEPS];
    __shared__ float nz_s[T_STEPS];

    for (int i = tid; i < T_STEPS; i += BLOCK) {
        ys_s[i] = ys[i];
        qs_s[i] = qs[i];
        nz_s[i] = noises[i * BS + blk];
    }

    const float sigb    = p_sigb[0];
    const float llr     = p_llr[0];
    const float llrd    = p_llrd[0];
    const float oscale  = p_oscale[0];
    const float ufs     = p_ufs[0];
    const float lwd     = p_lwd[0];
    const float qscale  = p_qscale[0];
    const float tauq_m1 = p_tauq[0];
    const float tauy_m1 = p_tauy[0];

    const float lr0      = expf(llr);
    const float lr_decay = expf(llrd);
    const float wd       = expf(lwd);
    const float rwd      = 1.0f / wd;
    const float tauq     = 1.0f + log1pf(expf(tauq_m1));
    const float tauy     = 1.0f + log1pf(expf(tauy_m1));
    const float omtq     = 1.0f - tauq;
    const float omty     = 1.0f - tauy;

    // Coefficients resident in registers as packed pairs: 3*16*2 = 96 VGPRs.
    const v4f* zb4 = (const v4f*)z_biases;
    const v4f* wi4 = (const v4f*)w_in;
    const v4f* wq4 = (const v4f*)w_inq;
    v2f cb[NP], cw[NP], cq[NP];
#pragma unroll
    for (int c = 0; c < NQ; ++c) {
        const int idx = tid + c * BLOCK;        // coalesced 16B/lane
        v4f b = zb4[idx];
        b *= sigb;
        v4f w = wi4[idx];
        v4f g = wq4[idx];
        cb[2*c]   = (v2f){b.x, b.y};  cb[2*c+1] = (v2f){b.z, b.w};
        cw[2*c]   = (v2f){w.x, w.y};  cw[2*c+1] = (v2f){w.z, w.w};
        cq[2*c]   = (v2f){g.x, g.y};  cq[2*c+1] = (v2f){g.z, g.w};
    }

    // Persistent per-thread state: 32 output weights in v-space (16 pairs).
    v2f v[NP];
#pragma unroll
    for (int i = 0; i < NP; ++i) v[i] = (v2f){0.0f, 0.0f};

    float u = 0.0f, e = 0.0f, lr_mult = 1.0f, qlp = 0.0f, ylp = 0.0f;
    float sp = 1.0f, rsp = 1.0f;        // wd^t and 1/wd^t

    __syncthreads();                    // single-wave block: nearly free, once

    float q_c = qs_s[0], y_c = ys_s[0], n_c = nz_s[0];

    for (int t = 0; t < T_STEPS; ++t) {
        const int tn = (t + 1 < T_STEPS) ? t + 1 : t;
        const float q_n = qs_s[tn], y_n = ys_s[tn], n_n = nz_s[tn];

        qlp = omtq * qlp + tauq * q_c;
        const float qsc = qscale * qlp;
        const float x   = fmaf(u, ufs, e) + n_c;
        const v2f xx = (v2f){x, x};
        const v2f qq = (v2f){qsc, qsc};

        v2f h[NP];
        v2f su_a[4], sh_a[4];
#pragma unroll
        for (int a = 0; a < 4; ++a) {
            su_a[a] = (v2f){0.0f, 0.0f};
            sh_a[a] = (v2f){0.0f, 0.0f};
        }
#pragma unroll
        for (int i = 0; i < NP; ++i) {   // fully unrolled: all indices static
            v2f t2 = pk_fma(qq, cq[i], cb[i]);
            t2 = pk_fma(xx, cw[i], t2);
            v2f hh;
            hh.x = fmaxf(t2.x, 0.0f);
            hh.y = fmaxf(t2.y, 0.0f);
            h[i] = hh;
            su_a[i & 3] = pk_fma(v[i], hh, su_a[i & 3]);
            sh_a[i & 3] = pk_fma(hh, hh, sh_a[i & 3]);
        }
        v2f su2 = pk_add(pk_add(su_a[0], su_a[1]), pk_add(su_a[2], su_a[3]));
        v2f sh2 = pk_add(pk_add(sh_a[0], sh_a[1]), pk_add(sh_a[2], sh_a[3]));
        float su_l = su2.x + su2.y;
        float sh_l = sh2.x + sh2.y;

        // Wave-only reduction: DPP to lane 63, then readlane -> SGPR broadcast.
        const float su_w = wave_sum_lane63(su_l);
        const float sh_w = wave_sum_lane63(sh_l);
        const float su_t = bcast63(su_w);
        const float sh_t = bcast63(sh_w);

        u = sp * su_t;                   // w_t = sp * v_t
        if (tid == 0) out[t * BS + blk] = oscale * u;

        ylp = omty * ylp + tauy * y_c;
        e = ylp - u;
        const float el = e * (lr0 * lr_mult);
        const float c  = el * rsp;       // dw coefficient in v-space
        const v2f cc = (v2f){c, c};

#pragma unroll
        for (int i = 0; i < NP; ++i)
            v[i] = pk_fma(cc, h[i], v[i]);

        const float nrm = sqrtf(fmaf(el * el, sh_t, FUDGE));
        lr_mult *= __expf(-lr_decay * nrm);
        sp  *= wd;
        rsp *= rwd;

        q_c = q_n; y_c = y_n; n_c = n_n;
    }
}

extern "C" void kernel_launch(void* const* d_in, const int* in_sizes, int n_in,
                              void* d_out, int out_size, void* d_ws, size_t ws_size,
                              hipStream_t stream) {
    (void)in_sizes; (void)n_in; (void)d_ws; (void)ws_size; (void)out_size;
    const float* noises   = (const float*)d_in[0];
    const float* ys       = (const float*)d_in[1];
    const float* qs       = (const float*)d_in[2];
    const float* z_biases = (const float*)d_in[3];
    const float* w_in     = (const float*)d_in[4];
    const float* w_inq    = (const float*)d_in[5];
    const float* llr      = (const float*)d_in[6];
    const float* llrd     = (const float*)d_in[7];
    const float* sigb     = (const float*)d_in[8];
    const float* oscale   = (const float*)d_in[9];
    const float* ufs      = (const float*)d_in[10];
    const float* lwd      = (const float*)d_in[11];
    const float* qscale   = (const float*)d_in[12];
    const float* tauq     = (const float*)d_in[13];
    const float* tauy     = (const float*)d_in[14];
    float* out = (float*)d_out;

    hipLaunchKernelGGL(legacy_elbo_scan_kernel, dim3(BS), dim3(BLOCK), 0, stream,
                       noises, ys, qs, z_biases, w_in, w_inq,
                       llr, llrd, sigb, oscale, ufs, lwd, qscale, tauq, tauy,
                       out);
}

// Round 2
// 217.983 us; speedup vs baseline: 1.0200x; 1.0200x over previous
//
#include <hip/hip_runtime.h>
#include <math.h>

#define T_STEPS 256
#define BS      512
#define N       2048
#define BLOCK   64                // ONE wave per batch element: no barriers, no LDS reduce
#define EPT     (N / BLOCK)       // 32 elements per thread
#define NP      (EPT / 2)         // 16 packed float2 per thread
#define NQ      (EPT / 4)         // 8 float4 loads per thread
#define FUDGE   1e-4f

typedef float v2f __attribute__((ext_vector_type(2)));
typedef float v4f __attribute__((ext_vector_type(4)));

// --- packed fp32 math (VOP3P, gfx90a+/gfx950). One instr = 2 lanes of fma. ---
__device__ __forceinline__ v2f pk_fma(v2f a, v2f b, v2f c) {
    v2f d;
    asm("v_pk_fma_f32 %0, %1, %2, %3" : "=v"(d) : "v"(a), "v"(b), "v"(c));
    return d;
}
__device__ __forceinline__ v2f pk_add(v2f a, v2f b) {
    v2f d;
    asm("v_pk_add_f32 %0, %1, %2" : "=v"(d) : "v"(a), "v"(b));
    return d;
}

// --- wave64 sum via DPP: lane 63 holds the wave total --------------------
template <int CTRL>
__device__ __forceinline__ float dpp_add(float v) {
    int sh = __builtin_amdgcn_update_dpp(0, __float_as_int(v), CTRL, 0xf, 0xf, true);
    return v + __int_as_float(sh);
}

__device__ __forceinline__ float wave_sum_lane63(float v) {
    v = dpp_add<0x111>(v);  // row_shr:1
    v = dpp_add<0x112>(v);  // row_shr:2
    v = dpp_add<0x114>(v);  // row_shr:4
    v = dpp_add<0x118>(v);  // row_shr:8
    v = dpp_add<0x142>(v);  // row_bcast:15
    v = dpp_add<0x143>(v);  // row_bcast:31
    return v;               // total valid in lane 63
}

__device__ __forceinline__ float bcast63(float v) {
    return __int_as_float(__builtin_amdgcn_readlane(__float_as_int(v), 63));
}

// R10: R9's structure was right but the register allocator sank the
// loop-invariant coefficient loads (cb/cw/cq, 96 VGPRs) back into the
// t-loop (VGPR_Count=100 proved it): ~48 global re-loads + addr math per
// step = the 1450 cy/step wall. Fix:
//  (a) amdgpu_waves_per_eu(1,1): 512-VGPR budget, so remat has no payoff
//      (grid is only 512 waves = 2/CU; occupancy is irrelevant).
//  (b) asm volatile "memory" clobber after the preload: the asm may write
//      the arrays, so sinking the loads past it is ILLEGAL, not just
//      unprofitable.
__global__ __launch_bounds__(BLOCK) __attribute__((amdgpu_waves_per_eu(1, 1)))
void legacy_elbo_scan_kernel(
    const float* __restrict__ noises,   // [T, BS]
    const float* __restrict__ ys,       // [T]
    const float* __restrict__ qs,       // [T]
    const float* __restrict__ z_biases, // [N]
    const float* __restrict__ w_in,     // [N]
    const float* __restrict__ w_inq,    // [N]
    const float* __restrict__ p_llr,
    const float* __restrict__ p_llrd,
    const float* __restrict__ p_sigb,
    const float* __restrict__ p_oscale,
    const float* __restrict__ p_ufs,
    const float* __restrict__ p_lwd,
    const float* __restrict__ p_qscale,
    const float* __restrict__ p_tauq,
    const float* __restrict__ p_tauy,
    float* __restrict__ out)            // [T, BS]
{
    const int tid = threadIdx.x;        // == lane
    const int blk = blockIdx.x;         // batch index k

    __shared__ float ys_s[T_STEPS];
    __shared__ float qs_s[T_STEPS];
    __shared__ float nz_s[T_STEPS];

    for (int i = tid; i < T_STEPS; i += BLOCK) {
        ys_s[i] = ys[i];
        qs_s[i] = qs[i];
        nz_s[i] = noises[i * BS + blk];
    }

    const float sigb    = p_sigb[0];
    const float llr     = p_llr[0];
    const float llrd    = p_llrd[0];
    const float oscale  = p_oscale[0];
    const float ufs     = p_ufs[0];
    const float lwd     = p_lwd[0];
    const float qscale  = p_qscale[0];
    const float tauq_m1 = p_tauq[0];
    const float tauy_m1 = p_tauy[0];

    const float lr0      = expf(llr);
    const float lr_decay = expf(llrd);
    const float wd       = expf(lwd);
    const float rwd      = 1.0f / wd;
    const float tauq     = 1.0f + log1pf(expf(tauq_m1));
    const float tauy     = 1.0f + log1pf(expf(tauy_m1));
    const float omtq     = 1.0f - tauq;
    const float omty     = 1.0f - tauy;

    // Coefficients resident in registers as packed pairs: 3*16*2 = 96 VGPRs.
    const v4f* zb4 = (const v4f*)z_biases;
    const v4f* wi4 = (const v4f*)w_in;
    const v4f* wq4 = (const v4f*)w_inq;
    v2f cb[NP], cw[NP], cq[NP];
#pragma unroll
    for (int c = 0; c < NQ; ++c) {
        const int idx = tid + c * BLOCK;        // coalesced 16B/lane
        v4f b = zb4[idx];
        b *= sigb;
        v4f w = wi4[idx];
        v4f g = wq4[idx];
        cb[2*c]   = (v2f){b.x, b.y};  cb[2*c+1] = (v2f){b.z, b.w};
        cw[2*c]   = (v2f){w.x, w.y};  cw[2*c+1] = (v2f){w.z, w.w};
        cq[2*c]   = (v2f){g.x, g.y};  cq[2*c+1] = (v2f){g.z, g.w};
    }

    // The asm may modify any memory => the coefficient loads above cannot
    // legally be re-executed (sunk) inside the t-loop. Values must stay in
    // registers (budget is 512 VGPRs at waves_per_eu(1,1); no spill).
    asm volatile("" ::: "memory");

    // Persistent per-thread state: 32 output weights in v-space (16 pairs).
    v2f v[NP];
#pragma unroll
    for (int i = 0; i < NP; ++i) v[i] = (v2f){0.0f, 0.0f};

    float u = 0.0f, e = 0.0f, lr_mult = 1.0f, qlp = 0.0f, ylp = 0.0f;
    float sp = 1.0f, rsp = 1.0f;        // wd^t and 1/wd^t

    __syncthreads();                    // single-wave block: nearly free, once

    float q_c = qs_s[0], y_c = ys_s[0], n_c = nz_s[0];

    for (int t = 0; t < T_STEPS; ++t) {
        const int tn = (t + 1 < T_STEPS) ? t + 1 : t;
        const float q_n = qs_s[tn], y_n = ys_s[tn], n_n = nz_s[tn];

        qlp = omtq * qlp + tauq * q_c;
        const float qsc = qscale * qlp;
        const float x   = fmaf(u, ufs, e) + n_c;
        const v2f xx = (v2f){x, x};
        const v2f qq = (v2f){qsc, qsc};

        v2f h[NP];
        v2f su_a[4], sh_a[4];
#pragma unroll
        for (int a = 0; a < 4; ++a) {
            su_a[a] = (v2f){0.0f, 0.0f};
            sh_a[a] = (v2f){0.0f, 0.0f};
        }
#pragma unroll
        for (int i = 0; i < NP; ++i) {   // fully unrolled: all indices static
            v2f t2 = pk_fma(qq, cq[i], cb[i]);
            t2 = pk_fma(xx, cw[i], t2);
            v2f hh;
            hh.x = fmaxf(t2.x, 0.0f);
            hh.y = fmaxf(t2.y, 0.0f);
            h[i] = hh;
            su_a[i & 3] = pk_fma(v[i], hh, su_a[i & 3]);
            sh_a[i & 3] = pk_fma(hh, hh, sh_a[i & 3]);
        }
        v2f su2 = pk_add(pk_add(su_a[0], su_a[1]), pk_add(su_a[2], su_a[3]));
        v2f sh2 = pk_add(pk_add(sh_a[0], sh_a[1]), pk_add(sh_a[2], sh_a[3]));
        float su_l = su2.x + su2.y;
        float sh_l = sh2.x + sh2.y;

        // Wave-only reduction: DPP to lane 63, then readlane -> SGPR broadcast.
        const float su_w = wave_sum_lane63(su_l);
        const float sh_w = wave_sum_lane63(sh_l);
        const float su_t = bcast63(su_w);
        const float sh_t = bcast63(sh_w);

        u = sp * su_t;                   // w_t = sp * v_t
        if (tid == 0) out[t * BS + blk] = oscale * u;

        ylp = omty * ylp + tauy * y_c;
        e = ylp - u;
        const float el = e * (lr0 * lr_mult);
        const float c  = el * rsp;       // dw coefficient in v-space
        const v2f cc = (v2f){c, c};

#pragma unroll
        for (int i = 0; i < NP; ++i)
            v[i] = pk_fma(cc, h[i], v[i]);

        const float nrm = sqrtf(fmaf(el * el, sh_t, FUDGE));
        lr_mult *= __expf(-lr_decay * nrm);
        sp  *= wd;
        rsp *= rwd;

        q_c = q_n; y_c = y_n; n_c = n_n;
    }
}

extern "C" void kernel_launch(void* const* d_in, const int* in_sizes, int n_in,
                              void* d_out, int out_size, void* d_ws, size_t ws_size,
                              hipStream_t stream) {
    (void)in_sizes; (void)n_in; (void)d_ws; (void)ws_size; (void)out_size;
    const float* noises   = (const float*)d_in[0];
    const float* ys       = (const float*)d_in[1];
    const float* qs       = (const float*)d_in[2];
    const float* z_biases = (const float*)d_in[3];
    const float* w_in     = (const float*)d_in[4];
    const float* w_inq    = (const float*)d_in[5];
    const float* llr      = (const float*)d_in[6];
    const float* llrd     = (const float*)d_in[7];
    const float* sigb     = (const float*)d_in[8];
    const float* oscale   = (const float*)d_in[9];
    const float* ufs      = (const float*)d_in[10];
    const float* lwd      = (const float*)d_in[11];
    const float* qscale   = (const float*)d_in[12];
    const float* tauq     = (const float*)d_in[13];
    const float* tauy     = (const float*)d_in[14];
    float* out = (float*)d_out;

    hipLaunchKernelGGL(legacy_elbo_scan_kernel, dim3(BS), dim3(BLOCK), 0, stream,
                       noises, ys, qs, z_biases, w_in, w_inq,
                       llr, llrd, sigb, oscale, ufs, lwd, qscale, tauq, tauy,
                       out);
}

// Round 3
// 217.391 us; speedup vs baseline: 1.0228x; 1.0027x over previous
//
#include <hip/hip_runtime.h>
#include <math.h>

#define T_STEPS 256
#define BS      512
#define N       2048
#define BLOCK   64                // ONE wave per batch element: no barriers, no LDS reduce
#define EPT     (N / BLOCK)       // 32 elements per thread
#define NP      (EPT / 2)         // 16 packed float2 per thread
#define NQ      (EPT / 4)         // 8 float4 loads per thread
#define FUDGE   1e-4f

typedef float v2f __attribute__((ext_vector_type(2)));
typedef float v4f __attribute__((ext_vector_type(4)));

// --- packed fp32 math (VOP3P, gfx90a+/gfx950). One instr = 2 lanes of fma. ---
__device__ __forceinline__ v2f pk_fma(v2f a, v2f b, v2f c) {
    v2f d;
    asm("v_pk_fma_f32 %0, %1, %2, %3" : "=v"(d) : "v"(a), "v"(b), "v"(c));
    return d;
}
__device__ __forceinline__ v2f pk_add(v2f a, v2f b) {
    v2f d;
    asm("v_pk_add_f32 %0, %1, %2" : "=v"(d) : "v"(a), "v"(b));
    return d;
}

// --- wave64 sum via DPP: lane 63 holds the wave total --------------------
template <int CTRL>
__device__ __forceinline__ float dpp_add(float v) {
    int sh = __builtin_amdgcn_update_dpp(0, __float_as_int(v), CTRL, 0xf, 0xf, true);
    return v + __int_as_float(sh);
}

__device__ __forceinline__ float wave_sum_lane63(float v) {
    v = dpp_add<0x111>(v);  // row_shr:1
    v = dpp_add<0x112>(v);  // row_shr:2
    v = dpp_add<0x114>(v);  // row_shr:4
    v = dpp_add<0x118>(v);  // row_shr:8
    v = dpp_add<0x142>(v);  // row_bcast:15
    v = dpp_add<0x143>(v);  // row_bcast:31
    return v;               // total valid in lane 63
}

__device__ __forceinline__ float bcast63(float v) {
    return __int_as_float(__builtin_amdgcn_readlane(__float_as_int(v), 63));
}

// R11: R10's hints (waves_per_eu(1,1) + blanket memory clobber) only got one
// of three coefficient arrays resident (VGPR_Count=132; ~48 of ~96 coeff
// regs). The loads for the rest are still sunk/refilled per step -- their
// ~200cy L2 latency sits on the h-compute critical path (wave is alone on
// its SIMD; nothing hides it). Escalation: per-value asm "+v" pins. Each
// coefficient value becomes the OUTPUT of an opaque asm -- remat of the load
// is impossible by construction; with the 512-VGPR budget the allocator has
// no reason to spill ~220 live values.
__global__ __launch_bounds__(BLOCK) __attribute__((amdgpu_waves_per_eu(1, 1)))
void legacy_elbo_scan_kernel(
    const float* __restrict__ noises,   // [T, BS]
    const float* __restrict__ ys,       // [T]
    const float* __restrict__ qs,       // [T]
    const float* __restrict__ z_biases, // [N]
    const float* __restrict__ w_in,     // [N]
    const float* __restrict__ w_inq,    // [N]
    const float* __restrict__ p_llr,
    const float* __restrict__ p_llrd,
    const float* __restrict__ p_sigb,
    const float* __restrict__ p_oscale,
    const float* __restrict__ p_ufs,
    const float* __restrict__ p_lwd,
    const float* __restrict__ p_qscale,
    const float* __restrict__ p_tauq,
    const float* __restrict__ p_tauy,
    float* __restrict__ out)            // [T, BS]
{
    const int tid = threadIdx.x;        // == lane
    const int blk = blockIdx.x;         // batch index k

    __shared__ float ys_s[T_STEPS];
    __shared__ float qs_s[T_STEPS];
    __shared__ float nz_s[T_STEPS];

    for (int i = tid; i < T_STEPS; i += BLOCK) {
        ys_s[i] = ys[i];
        qs_s[i] = qs[i];
        nz_s[i] = noises[i * BS + blk];
    }

    const float sigb    = p_sigb[0];
    const float llr     = p_llr[0];
    const float llrd    = p_llrd[0];
    const float oscale  = p_oscale[0];
    const float ufs     = p_ufs[0];
    const float lwd     = p_lwd[0];
    const float qscale  = p_qscale[0];
    const float tauq_m1 = p_tauq[0];
    const float tauy_m1 = p_tauy[0];

    const float lr0      = expf(llr);
    const float lr_decay = expf(llrd);
    const float wd       = expf(lwd);
    const float rwd      = 1.0f / wd;
    const float tauq     = 1.0f + log1pf(expf(tauq_m1));
    const float tauy     = 1.0f + log1pf(expf(tauy_m1));
    const float omtq     = 1.0f - tauq;
    const float omty     = 1.0f - tauy;

    // Coefficients resident in registers as packed pairs: 3*16*2 = 96 VGPRs.
    const v4f* zb4 = (const v4f*)z_biases;
    const v4f* wi4 = (const v4f*)w_in;
    const v4f* wq4 = (const v4f*)w_inq;
    v2f cb[NP], cw[NP], cq[NP];
#pragma unroll
    for (int c = 0; c < NQ; ++c) {
        const int idx = tid + c * BLOCK;        // coalesced 16B/lane
        v4f b = zb4[idx];
        b *= sigb;
        v4f w = wi4[idx];
        v4f g = wq4[idx];
        cb[2*c]   = (v2f){b.x, b.y};  cb[2*c+1] = (v2f){b.z, b.w};
        cw[2*c]   = (v2f){w.x, w.y};  cw[2*c+1] = (v2f){w.z, w.w};
        cq[2*c]   = (v2f){g.x, g.y};  cq[2*c+1] = (v2f){g.z, g.w};
    }

    // Per-value pins: each coefficient becomes the output of an opaque asm.
    // The loads above cannot be rematerialized into the loop -- the values
    // MUST live in VGPRs (512 budget at waves_per_eu(1,1); no spill payoff).
#pragma unroll
    for (int i = 0; i < NP; ++i) {
        asm volatile("" : "+v"(cb[i]));
        asm volatile("" : "+v"(cw[i]));
        asm volatile("" : "+v"(cq[i]));
    }

    // Persistent per-thread state: 32 output weights in v-space (16 pairs).
    v2f v[NP];
#pragma unroll
    for (int i = 0; i < NP; ++i) v[i] = (v2f){0.0f, 0.0f};

    float u = 0.0f, e = 0.0f, lr_mult = 1.0f, qlp = 0.0f, ylp = 0.0f;
    float sp = 1.0f, rsp = 1.0f;        // wd^t and 1/wd^t

    __syncthreads();                    // single-wave block: nearly free, once

    float q_c = qs_s[0], y_c = ys_s[0], n_c = nz_s[0];

    for (int t = 0; t < T_STEPS; ++t) {
        const int tn = (t + 1 < T_STEPS) ? t + 1 : t;
        const float q_n = qs_s[tn], y_n = ys_s[tn], n_n = nz_s[tn];

        qlp = omtq * qlp + tauq * q_c;
        const float qsc = qscale * qlp;
        const float x   = fmaf(u, ufs, e) + n_c;
        const v2f xx = (v2f){x, x};
        const v2f qq = (v2f){qsc, qsc};

        v2f h[NP];
        v2f su_a[4], sh_a[4];
#pragma unroll
        for (int a = 0; a < 4; ++a) {
            su_a[a] = (v2f){0.0f, 0.0f};
            sh_a[a] = (v2f){0.0f, 0.0f};
        }
#pragma unroll
        for (int i = 0; i < NP; ++i) {   // fully unrolled: all indices static
            v2f t2 = pk_fma(qq, cq[i], cb[i]);
            t2 = pk_fma(xx, cw[i], t2);
            v2f hh;
            hh.x = fmaxf(t2.x, 0.0f);
            hh.y = fmaxf(t2.y, 0.0f);
            h[i] = hh;
            su_a[i & 3] = pk_fma(v[i], hh, su_a[i & 3]);
            sh_a[i & 3] = pk_fma(hh, hh, sh_a[i & 3]);
        }
        v2f su2 = pk_add(pk_add(su_a[0], su_a[1]), pk_add(su_a[2], su_a[3]));
        v2f sh2 = pk_add(pk_add(sh_a[0], sh_a[1]), pk_add(sh_a[2], sh_a[3]));
        float su_l = su2.x + su2.y;
        float sh_l = sh2.x + sh2.y;

        // Wave-only reduction: DPP to lane 63, then readlane -> SGPR broadcast.
        const float su_w = wave_sum_lane63(su_l);
        const float sh_w = wave_sum_lane63(sh_l);
        const float su_t = bcast63(su_w);
        const float sh_t = bcast63(sh_w);

        u = sp * su_t;                   // w_t = sp * v_t
        if (tid == 0) out[t * BS + blk] = oscale * u;

        ylp = omty * ylp + tauy * y_c;
        e = ylp - u;
        const float el = e * (lr0 * lr_mult);
        const float c  = el * rsp;       // dw coefficient in v-space
        const v2f cc = (v2f){c, c};

#pragma unroll
        for (int i = 0; i < NP; ++i)
            v[i] = pk_fma(cc, h[i], v[i]);

        const float nrm = sqrtf(fmaf(el * el, sh_t, FUDGE));
        lr_mult *= __expf(-lr_decay * nrm);
        sp  *= wd;
        rsp *= rwd;

        q_c = q_n; y_c = y_n; n_c = n_n;
    }
}

extern "C" void kernel_launch(void* const* d_in, const int* in_sizes, int n_in,
                              void* d_out, int out_size, void* d_ws, size_t ws_size,
                              hipStream_t stream) {
    (void)in_sizes; (void)n_in; (void)d_ws; (void)ws_size; (void)out_size;
    const float* noises   = (const float*)d_in[0];
    const float* ys       = (const float*)d_in[1];
    const float* qs       = (const float*)d_in[2];
    const float* z_biases = (const float*)d_in[3];
    const float* w_in     = (const float*)d_in[4];
    const float* w_inq    = (const float*)d_in[5];
    const float* llr      = (const float*)d_in[6];
    const float* llrd     = (const float*)d_in[7];
    const float* sigb     = (const float*)d_in[8];
    const float* oscale   = (const float*)d_in[9];
    const float* ufs      = (const float*)d_in[10];
    const float* lwd      = (const float*)d_in[11];
    const float* qscale   = (const float*)d_in[12];
    const float* tauq     = (const float*)d_in[13];
    const float* tauy     = (const float*)d_in[14];
    float* out = (float*)d_out;

    hipLaunchKernelGGL(legacy_elbo_scan_kernel, dim3(BS), dim3(BLOCK), 0, stream,
                       noises, ys, qs, z_biases, w_in, w_inq,
                       llr, llrd, sigb, oscale, ufs, lwd, qscale, tauq, tauy,
                       out);
}